// Round 1
// 725.505 us; speedup vs baseline: 1.1465x; 1.1465x over previous
//
#include <hip/hip_runtime.h>
#include <stdint.h>

// HiPPO-LegT scan  ->  causal convolution  c_t = sum_k f_{t-k} * (A^k B)
// Prep: V[k] = A^k B built by log-doubling  V_{2m} = [V_m | A^m V_m]  (fp32),
// 9 wide dispatches instead of 46-deep serial matvec chains.
// Main: big f16 MFMA matmul C_bd = Toeplitz(rev f_bd) @ V, double-buffered LDS,
// one barrier per K-step, prefetch loads in flight across the barrier.

typedef _Float16 half8 __attribute__((ext_vector_type(8)));
typedef float floatx4 __attribute__((ext_vector_type(4)));

// ---------------- prep kernels (all fp32) ----------------

// At = A^T ; Vbuf row 0 = B
__global__ void k_at(const float* __restrict__ A, float* __restrict__ At,
                     const float* __restrict__ Bvec, float* __restrict__ Vbuf) {
    int i = blockIdx.x, j = threadIdx.x;
    At[j * 256 + i] = A[i * 256 + j];
    if (i == 0) Vbuf[j] = Bvec[j];
}

// g8[bd][r][i] = g[i+r] where g[x] = f[511-x] for x<=511 else 0 (fp16)
__global__ void k_g8(const float* __restrict__ inp, _Float16* __restrict__ g8) {
    int bd = blockIdx.x;
    const float* f = inp + (size_t)bd * 512;
    _Float16* g = g8 + (size_t)bd * 5248;
    for (int idx = threadIdx.x; idx < 5248; idx += 256) {
        int r = idx / 656;
        int i = idx - r * 656;
        int jj = i + r;
        float val = (jj < 512) ? f[511 - jj] : 0.f;
        g[idx] = (_Float16)val;
    }
}

// One doubling level. Blocks [0,256) (if do_sq): C = M@M and Ct = C^T.
// Blocks [256,256+m) (or [0,m) if !do_sq): Vbuf[m+j] = A^m @ Vbuf[j] via Mt.
// 1024 threads: r = tid&255 (output idx), kc = tid>>2^8 (split-K of 4x64).
__global__ __launch_bounds__(1024) void k_level(
    const float* __restrict__ M, const float* __restrict__ Mt,
    float* __restrict__ C, float* __restrict__ Ct,
    float* __restrict__ Vbuf, int m, int do_sq)
{
    __shared__ float vec[256];
    __shared__ float part[3][256];
    const int tid = threadIdx.x;
    const int r  = tid & 255;
    const int kc = tid >> 8;
    const int b  = blockIdx.x;
    const bool sq = (do_sq && b < 256);
    const int j = do_sq ? (b - 256) : b;          // valid only when !sq
    const float* Msrc;
    if (sq) {
        if (kc == 0) vec[r] = M[b * 256 + r];     // row b of A^m
        Msrc = M;
    } else {
        if (kc == 0) vec[r] = Vbuf[j * 256 + r];  // column j of V
        Msrc = Mt;
    }
    __syncthreads();
    const float* Mp = Msrc + (size_t)(kc * 64) * 256 + r;
    const float* vp = vec + kc * 64;
    float acc = 0.f;
#pragma unroll 8
    for (int k = 0; k < 64; ++k) acc += vp[k] * Mp[(size_t)k * 256];
    if (kc) part[kc - 1][r] = acc;
    __syncthreads();
    if (kc == 0) {
        acc += part[0][r] + part[1][r] + part[2][r];
        if (sq) {
            C[b * 256 + r]  = acc;
            Ct[r * 256 + b] = acc;
        } else {
            Vbuf[(m + j) * 256 + r] = acc;
        }
    }
}

// Vt[n][k] (fp16, row stride 512) from Vbuf[k][n] (fp32)
__global__ void k_vt(const float* __restrict__ Vbuf, _Float16* __restrict__ Vt) {
    int n = threadIdx.x;           // 0..255
    int k0 = blockIdx.x * 8;       // 64 blocks
    half8 wv;
#pragma unroll
    for (int i = 0; i < 8; ++i) wv[i] = (_Float16)Vbuf[(size_t)(k0 + i) * 256 + n];
    *reinterpret_cast<half8*>(Vt + (size_t)n * 512 + k0) = wv;
}

// ---------------- main MFMA kernel ----------------
// block: 128(t) x 256(n), 4 waves of 64x128, K-step 32, mfma_f32_16x16x32_f16
// Double-buffered ldsB, ONE barrier per K-step; next-tile global loads issued
// before the barrier so their latency hides under the MFMAs.
__global__ __launch_bounds__(256, 2) void k_main(
    const _Float16* __restrict__ g8,
    const _Float16* __restrict__ Vt,
    float* __restrict__ out)
{
    __shared__ _Float16 ldsA[8 * 656];       // 10496 B: 8 shifted copies of rev-f
    __shared__ _Float16 ldsB[2][256 * 40];   // 2 x 20480 B: 256 n-rows, 32 k + pad

    const int tid  = threadIdx.x;
    const int lane = tid & 63;
    const int w    = tid >> 6;
    const int bd   = blockIdx.x & 1023;
    const int tt   = blockIdx.x >> 10;    // 0..3
    const int t0   = 384 - 128 * tt;      // heavy blocks first
    const int Kmax = t0 + 128;

    // stage A copies (once per block)
    {
        const uint4* gsrc = reinterpret_cast<const uint4*>(g8 + (size_t)bd * 5248);
        uint4* adst = reinterpret_cast<uint4*>(ldsA);
        for (int idx = tid; idx < 656; idx += 256) adst[idx] = gsrc[idx];
    }

    const int wave_mt = (w & 1) << 6;     // 0 / 64
    const int wave_nn = (w >> 1) << 7;    // 0 / 128
    const int m16  = lane & 15;
    const int quad = lane >> 4;
    const int hi8  = quad << 3;

    // A-frag byte offsets (k0 added in loop): i0 = k0 + hi8 + (511 - t)
    int abase[4];
#pragma unroll
    for (int mf = 0; mf < 4; ++mf) {
        int t_lane = t0 + wave_mt + mf * 16 + m16;
        int c = 511 - t_lane;
        int rsh = (c + hi8) & 7;          // k0 % 32 == 0 keeps rsh constant
        abase[mf] = rsh * 1312 + 2 * (hi8 + c - rsh);
    }
    int bbase[8];
#pragma unroll
    for (int bf = 0; bf < 8; ++bf) {
        int n_row = wave_nn + bf * 16 + m16;
        bbase[bf] = n_row * 80 + hi8 * 2;
    }

    const int srow = tid >> 2;   // 0..63
    const int scol = tid & 3;    // 0..3
    const _Float16* vbase = Vt + (size_t)srow * 512 + scol * 8;

    // prologue: load + stage k0 = 0 into buffer 0
    uint4 st[4];
#pragma unroll
    for (int rr = 0; rr < 4; ++rr)
        st[rr] = *reinterpret_cast<const uint4*>(vbase + (size_t)rr * 64 * 512);
#pragma unroll
    for (int rr = 0; rr < 4; ++rr)
        *reinterpret_cast<uint4*>(reinterpret_cast<char*>(&ldsB[0][0])
                                  + (srow + rr * 64) * 80 + scol * 16) = st[rr];

    floatx4 acc[4][8];
#pragma unroll
    for (int mf = 0; mf < 4; ++mf)
#pragma unroll
        for (int bf = 0; bf < 8; ++bf) {
            floatx4 z = {0.f, 0.f, 0.f, 0.f};
            acc[mf][bf] = z;
        }

    int cur = 0;
    for (int k0 = 0; k0 < Kmax; k0 += 32) {
        const bool more = (k0 + 32 < Kmax);     // block-uniform
        if (more) {
            // issue next-tile loads NOW; they stay in flight across the barrier
#pragma unroll
            for (int rr = 0; rr < 4; ++rr)
                st[rr] = *reinterpret_cast<const uint4*>(
                    vbase + (size_t)rr * 64 * 512 + (k0 + 32));
        }
        __syncthreads();   // ldsB[cur] writes (prev iter) now visible

        half8 a[4], b[8];
        const char* aptr = reinterpret_cast<const char*>(ldsA) + 2 * k0;
#pragma unroll
        for (int mf = 0; mf < 4; ++mf)
            a[mf] = *reinterpret_cast<const half8*>(aptr + abase[mf]);
        const char* bptr = reinterpret_cast<const char*>(&ldsB[cur][0]);
#pragma unroll
        for (int bf = 0; bf < 8; ++bf)
            b[bf] = *reinterpret_cast<const half8*>(bptr + bbase[bf]);

#pragma unroll
        for (int mf = 0; mf < 4; ++mf)
#pragma unroll
            for (int bf = 0; bf < 8; ++bf)
                acc[mf][bf] = __builtin_amdgcn_mfma_f32_16x16x32_f16(
                    a[mf], b[bf], acc[mf][bf], 0, 0, 0);

        if (more) {
            // vmcnt wait lands here, after the MFMAs — latency hidden
            char* wdst = reinterpret_cast<char*>(&ldsB[cur ^ 1][0]);
#pragma unroll
            for (int rr = 0; rr < 4; ++rr)
                *reinterpret_cast<uint4*>(wdst + (srow + rr * 64) * 80 + scol * 16) = st[rr];
        }
        cur ^= 1;
    }

    // epilogue: C/D layout col=lane&15, row=quad*4+reg
#pragma unroll
    for (int mf = 0; mf < 4; ++mf) {
        int trow0 = t0 + wave_mt + mf * 16 + quad * 4;
#pragma unroll
        for (int bf = 0; bf < 8; ++bf) {
            int n = wave_nn + bf * 16 + m16;
#pragma unroll
            for (int reg = 0; reg < 4; ++reg) {
                int t = trow0 + reg;
                out[(size_t)t * 262144 + (size_t)bd * 256 + n] = acc[mf][bf][reg];
            }
        }
    }
}

// ---------------- launch ----------------

extern "C" void kernel_launch(void* const* d_in, const int* in_sizes, int n_in,
                              void* d_out, int out_size, void* d_ws, size_t ws_size,
                              hipStream_t stream) {
    const float* inputs = (const float*)d_in[0];   // (8,128,512)
    const float* A      = (const float*)d_in[1];   // (256,256)
    const float* Bvec   = (const float*)d_in[2];   // (256,)
    float* out = (float*)d_out;

    float* At   = (float*)d_ws;        // 65536 f
    float* M0   = At  + 65536;         // ping-pong A^m buffers (+ transposes)
    float* M0t  = M0  + 65536;
    float* M1   = M0t + 65536;
    float* M1t  = M1  + 65536;
    float* Vbuf = M1t + 65536;                    // 512 x 256 f32, row k = A^k B
    _Float16* Vt = (_Float16*)(Vbuf + 131072);    // 256 x 512 halves
    _Float16* g8 = Vt + 131072;                   // 1024 x 5248 halves

    k_g8 <<<1024, 256, 0, stream>>>(inputs, g8);
    k_at <<<256, 256, 0, stream>>>(A, At, Bvec, Vbuf);
    // doubling chain: level m squares A^m -> A^2m and expands V_m -> V_2m
    k_level<<<257, 1024, 0, stream>>>(A,  At,  M0, M0t, Vbuf,   1, 1); // A2 ->M0
    k_level<<<258, 1024, 0, stream>>>(M0, M0t, M1, M1t, Vbuf,   2, 1); // A4 ->M1
    k_level<<<260, 1024, 0, stream>>>(M1, M1t, M0, M0t, Vbuf,   4, 1); // A8 ->M0
    k_level<<<264, 1024, 0, stream>>>(M0, M0t, M1, M1t, Vbuf,   8, 1); // A16->M1
    k_level<<<272, 1024, 0, stream>>>(M1, M1t, M0, M0t, Vbuf,  16, 1); // A32->M0
    k_level<<<288, 1024, 0, stream>>>(M0, M0t, M1, M1t, Vbuf,  32, 1); // A64->M1
    k_level<<<320, 1024, 0, stream>>>(M1, M1t, M0, M0t, Vbuf,  64, 1); // A128->M0
    k_level<<<384, 1024, 0, stream>>>(M0, M0t, M1, M1t, Vbuf, 128, 1); // A256->M1
    k_level<<<256, 1024, 0, stream>>>(M1, M1t, M0, M0t, Vbuf, 256, 0); // expand only
    k_vt  <<<64, 256, 0, stream>>>(Vbuf, Vt);
    k_main<<<4096, 256, 0, stream>>>(g8, Vt, out);
}

// Round 2
// 617.813 us; speedup vs baseline: 1.3463x; 1.1743x over previous
//
#include <hip/hip_runtime.h>
#include <stdint.h>

// HiPPO-LegT scan  ->  causal convolution  c_t = sum_k f_{t-k} * (A^k B)
// Prep: V[k] = A^k B built by log-doubling  V_{2m} = [V_m | A^m V_m]  (fp32).
// Main: f16 MFMA matmul C_bd = Toeplitz(rev f_bd) @ V.  B-fragments are read
// DIRECTLY from global (Vb is 256 KiB, L2-resident) in coalesced dwordx4 form;
// only the tiny per-block Toeplitz A-tile lives in LDS.  K-loop has ZERO
// barriers -> no vmcnt(0) drain; 1-deep register double-buffer pipelines loads.

typedef _Float16 half8 __attribute__((ext_vector_type(8)));
typedef float floatx4 __attribute__((ext_vector_type(4)));

// ---------------- prep kernels (all fp32) ----------------

// At = A^T ; Vbuf row 0 = B
__global__ void k_at(const float* __restrict__ A, float* __restrict__ At,
                     const float* __restrict__ Bvec, float* __restrict__ Vbuf) {
    int i = blockIdx.x, j = threadIdx.x;
    At[j * 256 + i] = A[i * 256 + j];
    if (i == 0) Vbuf[j] = Bvec[j];
}

// g8[bd][r][i] = g[i+r] where g[x] = f[511-x] for x<=511 else 0 (fp16)
__global__ void k_g8(const float* __restrict__ inp, _Float16* __restrict__ g8) {
    int bd = blockIdx.x;
    const float* f = inp + (size_t)bd * 512;
    _Float16* g = g8 + (size_t)bd * 5248;
    for (int idx = threadIdx.x; idx < 5248; idx += 256) {
        int r = idx / 656;
        int i = idx - r * 656;
        int jj = i + r;
        float val = (jj < 512) ? f[511 - jj] : 0.f;
        g[idx] = (_Float16)val;
    }
}

// One doubling level. Blocks [0,256) (if do_sq): C = M@M and Ct = C^T.
// Blocks [256,256+m) (or [0,m) if !do_sq): Vbuf[m+j] = A^m @ Vbuf[j] via Mt.
__global__ __launch_bounds__(1024) void k_level(
    const float* __restrict__ M, const float* __restrict__ Mt,
    float* __restrict__ C, float* __restrict__ Ct,
    float* __restrict__ Vbuf, int m, int do_sq)
{
    __shared__ float vec[256];
    __shared__ float part[3][256];
    const int tid = threadIdx.x;
    const int r  = tid & 255;
    const int kc = tid >> 8;
    const int b  = blockIdx.x;
    const bool sq = (do_sq && b < 256);
    const int j = do_sq ? (b - 256) : b;          // valid only when !sq
    const float* Msrc;
    if (sq) {
        if (kc == 0) vec[r] = M[b * 256 + r];     // row b of A^m
        Msrc = M;
    } else {
        if (kc == 0) vec[r] = Vbuf[j * 256 + r];  // column j of V
        Msrc = Mt;
    }
    __syncthreads();
    const float* Mp = Msrc + (size_t)(kc * 64) * 256 + r;
    const float* vp = vec + kc * 64;
    float acc = 0.f;
#pragma unroll 8
    for (int k = 0; k < 64; ++k) acc += vp[k] * Mp[(size_t)k * 256];
    if (kc) part[kc - 1][r] = acc;
    __syncthreads();
    if (kc == 0) {
        acc += part[0][r] + part[1][r] + part[2][r];
        if (sq) {
            C[b * 256 + r]  = acc;
            Ct[r * 256 + b] = acc;
        } else {
            Vbuf[(m + j) * 256 + r] = acc;
        }
    }
}

// Vb[kb][n][j] = V[kb*8+j][n]  (fp16), kb=0..63 — MFMA-B-fragment-major layout
// so a lane's 8-k window at row n is one contiguous 16B global load.
__global__ void k_vb(const float* __restrict__ Vbuf, _Float16* __restrict__ Vb) {
    int n = threadIdx.x;           // 0..255
    int kb = blockIdx.x;           // 0..63
    half8 wv;
#pragma unroll
    for (int j = 0; j < 8; ++j) wv[j] = (_Float16)Vbuf[(size_t)(kb * 8 + j) * 256 + n];
    *reinterpret_cast<half8*>(Vb + (size_t)kb * 2048 + n * 8) = wv;
}

// ---------------- main MFMA kernel ----------------
// block: 128(t) x 256(n), 4 waves of 64x128, K-step 32, mfma_f32_16x16x32_f16
// A-frags from LDS (staged once, ONE barrier total); B-frags straight from
// global Vb (L2-resident) via coalesced dwordx4; register double-buffer.
__global__ __launch_bounds__(256, 2) void k_main(
    const _Float16* __restrict__ g8,
    const _Float16* __restrict__ Vb,
    float* __restrict__ out)
{
    __shared__ _Float16 ldsA[8 * 656];    // 10496 B: 8 shifted copies of rev-f

    const int tid  = threadIdx.x;
    const int lane = tid & 63;
    const int w    = tid >> 6;
    const int bd   = blockIdx.x & 1023;
    const int tt   = blockIdx.x >> 10;    // 0..3
    const int t0   = 384 - 128 * tt;      // heavy blocks first
    const int Kmax = t0 + 128;            // 512/384/256/128 — multiple of 64

    // stage A copies (once per block)
    {
        const uint4* gsrc = reinterpret_cast<const uint4*>(g8 + (size_t)bd * 5248);
        uint4* adst = reinterpret_cast<uint4*>(ldsA);
        for (int idx = tid; idx < 656; idx += 256) adst[idx] = gsrc[idx];
    }

    const int wave_mt = (w & 1) << 6;     // 0 / 64
    const int wave_nn = (w >> 1) << 7;    // 0 / 128
    const int m16  = lane & 15;
    const int quad = lane >> 4;
    const int hi8  = quad << 3;

    // A-frag byte offsets (k0 added in loop): i0 = k0 + hi8 + (511 - t)
    int abase[4];
#pragma unroll
    for (int mf = 0; mf < 4; ++mf) {
        int t_lane = t0 + wave_mt + mf * 16 + m16;
        int c = 511 - t_lane;
        int rsh = (c + hi8) & 7;          // k0 % 32 == 0 keeps rsh constant
        abase[mf] = rsh * 1312 + 2 * (hi8 + c - rsh);
    }
    // B-frag offsets into Vb (halves): kb-block from quad, row n, 8-k window
    int bidx[8];
#pragma unroll
    for (int bf = 0; bf < 8; ++bf) {
        int n_row = wave_nn + bf * 16 + m16;
        bidx[bf] = quad * 2048 + n_row * 8;
    }

    floatx4 acc[4][8];
#pragma unroll
    for (int mf = 0; mf < 4; ++mf)
#pragma unroll
        for (int bf = 0; bf < 8; ++bf) {
            floatx4 z = {0.f, 0.f, 0.f, 0.f};
            acc[mf][bf] = z;
        }

    half8 aA[4], aB[4], bA[8], bB[8];

    // prefetch B(k0=0) BEFORE the barrier (no LDS dependency)
#pragma unroll
    for (int bf = 0; bf < 8; ++bf)
        bA[bf] = *reinterpret_cast<const half8*>(Vb + bidx[bf]);

    __syncthreads();   // ldsA ready — the ONLY barrier in this kernel

    const char* aptr0 = reinterpret_cast<const char*>(ldsA);
#pragma unroll
    for (int mf = 0; mf < 4; ++mf)
        aA[mf] = *reinterpret_cast<const half8*>(aptr0 + abase[mf]);

    for (int k0 = 0; k0 < Kmax; k0 += 64) {
        // prefetch k0+32 into B set (always valid: Kmax % 64 == 0)
        {
            const _Float16* vb = Vb + ((size_t)(k0 + 32) << 8);
#pragma unroll
            for (int bf = 0; bf < 8; ++bf)
                bB[bf] = *reinterpret_cast<const half8*>(vb + bidx[bf]);
            const char* ap = aptr0 + 2 * (k0 + 32);
#pragma unroll
            for (int mf = 0; mf < 4; ++mf)
                aB[mf] = *reinterpret_cast<const half8*>(ap + abase[mf]);
        }
        __builtin_amdgcn_s_setprio(1);
#pragma unroll
        for (int mf = 0; mf < 4; ++mf)
#pragma unroll
            for (int bf = 0; bf < 8; ++bf)
                acc[mf][bf] = __builtin_amdgcn_mfma_f32_16x16x32_f16(
                    aA[mf], bA[bf], acc[mf][bf], 0, 0, 0);
        __builtin_amdgcn_s_setprio(0);

        if (k0 + 64 < Kmax) {   // prefetch k0+64 into A set
            const _Float16* vb = Vb + ((size_t)(k0 + 64) << 8);
#pragma unroll
            for (int bf = 0; bf < 8; ++bf)
                bA[bf] = *reinterpret_cast<const half8*>(vb + bidx[bf]);
            const char* ap = aptr0 + 2 * (k0 + 64);
#pragma unroll
            for (int mf = 0; mf < 4; ++mf)
                aA[mf] = *reinterpret_cast<const half8*>(ap + abase[mf]);
        }
        __builtin_amdgcn_s_setprio(1);
#pragma unroll
        for (int mf = 0; mf < 4; ++mf)
#pragma unroll
            for (int bf = 0; bf < 8; ++bf)
                acc[mf][bf] = __builtin_amdgcn_mfma_f32_16x16x32_f16(
                    aB[mf], bB[bf], acc[mf][bf], 0, 0, 0);
        __builtin_amdgcn_s_setprio(0);
    }

    // epilogue: C/D layout col=lane&15, row=quad*4+reg
#pragma unroll
    for (int mf = 0; mf < 4; ++mf) {
        int trow0 = t0 + wave_mt + mf * 16 + quad * 4;
#pragma unroll
        for (int bf = 0; bf < 8; ++bf) {
            int n = wave_nn + bf * 16 + m16;
#pragma unroll
            for (int reg = 0; reg < 4; ++reg) {
                int t = trow0 + reg;
                out[(size_t)t * 262144 + (size_t)bd * 256 + n] = acc[mf][bf][reg];
            }
        }
    }
}

// ---------------- launch ----------------

extern "C" void kernel_launch(void* const* d_in, const int* in_sizes, int n_in,
                              void* d_out, int out_size, void* d_ws, size_t ws_size,
                              hipStream_t stream) {
    const float* inputs = (const float*)d_in[0];   // (8,128,512)
    const float* A      = (const float*)d_in[1];   // (256,256)
    const float* Bvec   = (const float*)d_in[2];   // (256,)
    float* out = (float*)d_out;

    float* At   = (float*)d_ws;        // 65536 f
    float* M0   = At  + 65536;         // ping-pong A^m buffers (+ transposes)
    float* M0t  = M0  + 65536;
    float* M1   = M0t + 65536;
    float* M1t  = M1  + 65536;
    float* Vbuf = M1t + 65536;                    // 512 x 256 f32, row k = A^k B
    _Float16* Vb = (_Float16*)(Vbuf + 131072);    // 64 x 256 x 8 halves
    _Float16* g8 = Vb + 131072;                   // 1024 x 5248 halves

    k_g8 <<<1024, 256, 0, stream>>>(inputs, g8);
    k_at <<<256, 256, 0, stream>>>(A, At, Bvec, Vbuf);
    // doubling chain: level m squares A^m -> A^2m and expands V_m -> V_2m
    k_level<<<257, 1024, 0, stream>>>(A,  At,  M0, M0t, Vbuf,   1, 1); // A2 ->M0
    k_level<<<258, 1024, 0, stream>>>(M0, M0t, M1, M1t, Vbuf,   2, 1); // A4 ->M1
    k_level<<<260, 1024, 0, stream>>>(M1, M1t, M0, M0t, Vbuf,   4, 1); // A8 ->M0
    k_level<<<264, 1024, 0, stream>>>(M0, M0t, M1, M1t, Vbuf,   8, 1); // A16->M1
    k_level<<<272, 1024, 0, stream>>>(M1, M1t, M0, M0t, Vbuf,  16, 1); // A32->M0
    k_level<<<288, 1024, 0, stream>>>(M0, M0t, M1, M1t, Vbuf,  32, 1); // A64->M1
    k_level<<<320, 1024, 0, stream>>>(M1, M1t, M0, M0t, Vbuf,  64, 1); // A128->M0
    k_level<<<384, 1024, 0, stream>>>(M0, M0t, M1, M1t, Vbuf, 128, 1); // A256->M1
    k_level<<<256, 1024, 0, stream>>>(M1, M1t, M0, M0t, Vbuf, 256, 0); // expand only
    k_vb  <<<64, 256, 0, stream>>>(Vbuf, Vb);
    k_main<<<4096, 256, 0, stream>>>(g8, Vb, out);
}